// Round 5
// baseline (203.177 us; speedup 1.0000x reference)
//
#include <hip/hip_runtime.h>
#include <hip/hip_cooperative_groups.h>
#include <stdint.h>

namespace cg = cooperative_groups;

#define N_ATOMS 2048
#define NREP    27
#define NCAND   (NREP * N_ATOMS)        // 55296
#define KNN     12
#define CAP     128                      // LDS threshold-filter capacity
#define CAPC    8192                     // compacted candidate capacity
#define NEDGE   (N_ATOMS * KNN)
#define COOP_GRID 1024                   // 4 blocks/CU: guaranteed co-resident
#define OFF_EDGE 0
#define OFF_DIST (3 * NEDGE)
#define OFF_SRC  (OFF_DIST + NEDGE)
#define OFF_DST  (OFF_SRC + NEDGE)
#define OFF_NUM  (OFF_DST + NEDGE)
// d_ws: [0..4) u32 counter (memset 0) | [256..) float4 cand[CAPC] | u32 cidx[CAPC]
#define WS_CAND_OFF 256
#define WS_IDX_OFF  (WS_CAND_OFF + CAPC * 16)

// ---- shared device helpers (bit-identical chains across all kernels) -------
__device__ __forceinline__ void inv_cell(const float* c, float* M) {
    double a00 = c[0], a01 = c[1], a02 = c[2];
    double a10 = c[3], a11 = c[4], a12 = c[5];
    double a20 = c[6], a21 = c[7], a22 = c[8];
    double det = a00 * (a11 * a22 - a12 * a21)
               - a01 * (a10 * a22 - a12 * a20)
               + a02 * (a10 * a21 - a11 * a20);
    double id = 1.0 / det;
    M[0] = (float)(( a11 * a22 - a12 * a21) * id);
    M[1] = (float)((-(a01 * a22 - a02 * a21)) * id);
    M[2] = (float)(( a01 * a12 - a02 * a11) * id);
    M[3] = (float)((-(a10 * a22 - a12 * a20)) * id);
    M[4] = (float)(( a00 * a22 - a02 * a20) * id);
    M[5] = (float)((-(a00 * a12 - a02 * a10)) * id);
    M[6] = (float)(( a10 * a21 - a11 * a20) * id);
    M[7] = (float)((-(a00 * a21 - a01 * a20)) * id);
    M[8] = (float)(( a00 * a11 - a01 * a10) * id);
}

// classify candidate g = j*2048+i: compute pos_sc and validity (ref chains)
__device__ __forceinline__ bool classify(
    int g, const float* __restrict__ pos, const float* c, const float* M,
    float& px, float& py, float& pz)
{
    int j = g >> 11, i = g & (N_ATOMS - 1);
    float o0 = (float)(j / 9 - 1);
    float o1 = (float)((j / 3) % 3 - 1);
    float o2 = (float)(j % 3 - 1);
    float sx = __fadd_rn(__fadd_rn(__fmul_rn(o0, c[0]), __fmul_rn(o1, c[3])), __fmul_rn(o2, c[6]));
    float sy = __fadd_rn(__fadd_rn(__fmul_rn(o0, c[1]), __fmul_rn(o1, c[4])), __fmul_rn(o2, c[7]));
    float sz = __fadd_rn(__fadd_rn(__fmul_rn(o0, c[2]), __fmul_rn(o1, c[5])), __fmul_rn(o2, c[8]));
    px = __fadd_rn(pos[i * 3 + 0], sx);
    py = __fadd_rn(pos[i * 3 + 1], sy);
    pz = __fadd_rn(pos[i * 3 + 2], sz);
    float rn0 = sqrtf(c[0]*c[0] + c[1]*c[1] + c[2]*c[2]);
    float rn1 = sqrtf(c[3]*c[3] + c[4]*c[4] + c[5]*c[5]);
    float rn2 = sqrtf(c[6]*c[6] + c[7]*c[7] + c[8]*c[8]);
    float dxm = 0.1f * fminf(rn0, fminf(rn1, rn2));
    float f0 = __fmaf_rn(pz, M[6], __fmaf_rn(py, M[3], __fmul_rn(px, M[0])));
    float f1 = __fmaf_rn(pz, M[7], __fmaf_rn(py, M[4], __fmul_rn(px, M[1])));
    float f2 = __fmaf_rn(pz, M[8], __fmaf_rn(py, M[5], __fmul_rn(px, M[2])));
    return (f0 >= -(dxm / rn0)) && (f0 <= 1.0f + dxm / rn0)
        && (f1 >= -(dxm / rn1)) && (f1 <= 1.0f + dxm / rn1)
        && (f2 >= -(dxm / rn2)) && (f2 <= 1.0f + dxm / rn2);
}

__device__ __forceinline__ void emit_edges(
    int a, int r, unsigned mm, float d2, const float* __restrict__ pos,
    const float* c, float cx, float cy, float cz, float* __restrict__ out)
{
    int jj = (int)(mm >> 11), ii = (int)(mm & (N_ATOMS - 1));
    float o0 = (float)(jj / 9 - 1);
    float o1 = (float)((jj / 3) % 3 - 1);
    float o2 = (float)(jj % 3 - 1);
    float sx = __fadd_rn(__fadd_rn(__fmul_rn(o0, c[0]), __fmul_rn(o1, c[3])), __fmul_rn(o2, c[6]));
    float sy = __fadd_rn(__fadd_rn(__fmul_rn(o0, c[1]), __fmul_rn(o1, c[4])), __fmul_rn(o2, c[7]));
    float sz = __fadd_rn(__fadd_rn(__fmul_rn(o0, c[2]), __fmul_rn(o1, c[5])), __fmul_rn(o2, c[8]));
    float px = __fadd_rn(pos[ii * 3 + 0], sx);
    float py = __fadd_rn(pos[ii * 3 + 1], sy);
    float pz = __fadd_rn(pos[ii * 3 + 2], sz);
    int e = a * KNN + r;
    out[OFF_EDGE + 3 * e + 0] = __fsub_rn(px, cx);
    out[OFF_EDGE + 3 * e + 1] = __fsub_rn(py, cy);
    out[OFF_EDGE + 3 * e + 2] = __fsub_rn(pz, cz);
    out[OFF_DIST + e] = sqrtf(fmaxf(d2, 0.0f));
    out[OFF_SRC + e]  = (float)(mm & (N_ATOMS - 1));
    out[OFF_DST + e]  = (float)a;
}

__device__ __forceinline__ float init_T(const float* c) {
    float vol = fabsf(c[0] * (c[4] * c[8] - c[5] * c[7])
                    - c[1] * (c[3] * c[8] - c[5] * c[6])
                    + c[2] * (c[3] * c[7] - c[4] * c[6]));
    return powf(3.0f * 48.0f * vol / (4.0f * 3.14159265f * (float)N_ATOMS), 2.0f / 3.0f);
}

// ---------------------------------------------------------------------------
// Cooperative fused kernel: 1024 blocks x 256. Phase A classify+compact,
// grid.sync, Phase B scan (2 atoms per block).
// ---------------------------------------------------------------------------
__global__ __launch_bounds__(256, 4) void knn_coop(
    const float* __restrict__ pos, const float* __restrict__ cell,
    const int* __restrict__ numbers, unsigned* __restrict__ hdr,
    float4* __restrict__ cand, unsigned* __restrict__ cidx,
    float* __restrict__ out)
{
    __shared__ unsigned long long sh_keys[CAP];
    __shared__ int sh_cnt;

    const int tid = threadIdx.x;
    const int g = blockIdx.x * 256 + tid;

    float c[9];
#pragma unroll
    for (int q = 0; q < 9; ++q) c[q] = cell[q];

    // ---------------- Phase A ----------------
    if (g < NCAND) {
        float M[9];
        inv_cell(c, M);
        float px, py, pz;
        bool valid = classify(g, pos, c, M, px, py, pz);

        unsigned long long ball = __ballot(valid);
        int lane = tid & 63;
        int nv = __popcll(ball);
        unsigned base = 0;
        if (lane == 0 && nv) base = atomicAdd(hdr, (unsigned)nv);
        base = __shfl(base, 0, 64);
        if (valid) {
            unsigned s = base + __popcll(ball & ((1ull << lane) - 1ull));
            if (s < CAPC) {
                float pp = __fadd_rn(__fadd_rn(__fmul_rn(px, px), __fmul_rn(py, py)), __fmul_rn(pz, pz));
                cand[s] = make_float4(px, py, pz, pp);
                cidx[s] = (unsigned)g;
            }
        }
    }
    if (g < N_ATOMS) out[OFF_NUM + g] = (float)numbers[g];

    cg::this_grid().sync();

    // ---------------- Phase B: 2 atoms per block ----------------
    const int cnt_c = min((int)hdr[0], CAPC);
    const float T0 = init_T(c);

    for (int a = blockIdx.x; a < N_ATOMS; a += COOP_GRID) {
        const float cx = pos[a * 3 + 0];
        const float cy = pos[a * 3 + 1];
        const float cz = pos[a * 3 + 2];
        const float cc = __fadd_rn(__fadd_rn(__fmul_rn(cx, cx), __fmul_rn(cy, cy)), __fmul_rn(cz, cz));
        const int self_m = 13 * N_ATOMS + a;
        float T = T0;
        int cnt = 0;

        for (int att = 0; att < 16; ++att) {
            if (tid == 0) sh_cnt = 0;
            __syncthreads();
            for (int i = tid; i < cnt_c; i += 256) {
                float4 p = cand[i];
                float dot = __fmaf_rn(cz, p.z, __fmaf_rn(cy, p.y, __fmul_rn(cx, p.x)));
                float d2 = __fsub_rn(__fadd_rn(cc, p.w), __fmul_rn(2.0f, dot));
                if (d2 < T) {
                    unsigned mi = cidx[i];
                    if ((int)mi != self_m) {
                        int slot = atomicAdd(&sh_cnt, 1);
                        if (slot < CAP)
                            sh_keys[slot] = ((unsigned long long)__float_as_uint(d2) << 32) | mi;
                    }
                }
            }
            __syncthreads();
            cnt = sh_cnt;
            __syncthreads();
            if (cnt >= KNN && cnt <= CAP) break;
            T = (cnt < KNN) ? T * 2.0f : T * 0.5f;
        }

        if (tid < 64) {
            const unsigned long long MAXK = ~0ull;
            unsigned long long k0 = (tid < cnt) ? sh_keys[tid] : MAXK;
            unsigned long long k1 = (tid + 64 < cnt) ? sh_keys[tid + 64] : MAXK;
            unsigned long long lo = (k0 < k1) ? k0 : k1;
            unsigned long long hi = (k0 < k1) ? k1 : k0;
#pragma unroll
            for (int r = 0; r < KNN; ++r) {
                unsigned long long mn = lo;
#pragma unroll
                for (int off = 32; off; off >>= 1) {
                    unsigned long long o = __shfl_xor(mn, off, 64);
                    mn = (o < mn) ? o : mn;
                }
                if (lo == mn) { lo = hi; hi = MAXK; }
                if (tid == r)
                    emit_edges(a, r, (unsigned)(mn & 0xffffffffu),
                               __uint_as_float((unsigned)(mn >> 32)),
                               pos, c, cx, cy, cz, out);
            }
        }
        __syncthreads();   // protect sh_keys/sh_cnt before next atom
    }
}

// ---------------------------------------------------------------------------
// Fallback two-kernel path (R2, passing at 80.65 us) — verbatim structure.
// ---------------------------------------------------------------------------
__global__ __launch_bounds__(256) void prep_kernel(
    const float* __restrict__ pos, const float* __restrict__ cell,
    const int* __restrict__ numbers, unsigned* __restrict__ hdr,
    float4* __restrict__ cand, unsigned* __restrict__ cidx,
    float* __restrict__ out)
{
    int m = blockIdx.x * 256 + threadIdx.x;
    float c[9];
#pragma unroll
    for (int q = 0; q < 9; ++q) c[q] = cell[q];
    float M[9];
    inv_cell(c, M);
    float px, py, pz;
    bool valid = classify(m, pos, c, M, px, py, pz);

    unsigned long long ball = __ballot(valid);
    int lane = threadIdx.x & 63;
    int nv = __popcll(ball);
    unsigned base = 0;
    if (lane == 0 && nv) base = atomicAdd(hdr, (unsigned)nv);
    base = __shfl(base, 0, 64);
    if (valid) {
        unsigned s = base + __popcll(ball & ((1ull << lane) - 1ull));
        if (s < CAPC) {
            float pp = __fadd_rn(__fadd_rn(__fmul_rn(px, px), __fmul_rn(py, py)), __fmul_rn(pz, pz));
            cand[s] = make_float4(px, py, pz, pp);
            cidx[s] = (unsigned)m;
        }
    }
    if (m < N_ATOMS) out[OFF_NUM + m] = (float)numbers[m];
}

__global__ __launch_bounds__(256) void knn_kernel(
    const float* __restrict__ pos, const float* __restrict__ cell,
    const unsigned* __restrict__ hdr, const float4* __restrict__ cand,
    const unsigned* __restrict__ cidx, float* __restrict__ out)
{
    __shared__ unsigned long long sh_keys[CAP];
    __shared__ int sh_cnt;

    const int a = blockIdx.x;
    const int tid = threadIdx.x;

    float c[9];
#pragma unroll
    for (int q = 0; q < 9; ++q) c[q] = cell[q];

    const float cx = pos[a * 3 + 0];
    const float cy = pos[a * 3 + 1];
    const float cz = pos[a * 3 + 2];
    const float cc = __fadd_rn(__fadd_rn(__fmul_rn(cx, cx), __fmul_rn(cy, cy)), __fmul_rn(cz, cz));

    const int cnt_c = min((int)hdr[0], CAPC);
    float T = init_T(c);
    const int self_m = 13 * N_ATOMS + a;
    int cnt = 0;

    for (int att = 0; att < 16; ++att) {
        if (tid == 0) sh_cnt = 0;
        __syncthreads();
        for (int i = tid; i < cnt_c; i += 256) {
            float4 p = cand[i];
            float dot = __fmaf_rn(cz, p.z, __fmaf_rn(cy, p.y, __fmul_rn(cx, p.x)));
            float d2 = __fsub_rn(__fadd_rn(cc, p.w), __fmul_rn(2.0f, dot));
            if (d2 < T) {
                unsigned mi = cidx[i];
                if ((int)mi != self_m) {
                    int slot = atomicAdd(&sh_cnt, 1);
                    if (slot < CAP)
                        sh_keys[slot] = ((unsigned long long)__float_as_uint(d2) << 32) | mi;
                }
            }
        }
        __syncthreads();
        cnt = sh_cnt;
        __syncthreads();
        if (cnt >= KNN && cnt <= CAP) break;
        T = (cnt < KNN) ? T * 2.0f : T * 0.5f;
    }

    if (tid < 64) {
        const unsigned long long MAXK = ~0ull;
        unsigned long long k0 = (tid < cnt) ? sh_keys[tid] : MAXK;
        unsigned long long k1 = (tid + 64 < cnt) ? sh_keys[tid + 64] : MAXK;
        unsigned long long lo = (k0 < k1) ? k0 : k1;
        unsigned long long hi = (k0 < k1) ? k1 : k0;
#pragma unroll
        for (int r = 0; r < KNN; ++r) {
            unsigned long long mn = lo;
#pragma unroll
            for (int off = 32; off; off >>= 1) {
                unsigned long long o = __shfl_xor(mn, off, 64);
                mn = (o < mn) ? o : mn;
            }
            if (lo == mn) { lo = hi; hi = MAXK; }
            if (tid == r)
                emit_edges(a, r, (unsigned)(mn & 0xffffffffu),
                           __uint_as_float((unsigned)(mn >> 32)),
                           pos, c, cx, cy, cz, out);
        }
    }
}

extern "C" void kernel_launch(void* const* d_in, const int* in_sizes, int n_in,
                              void* d_out, int out_size, void* d_ws, size_t ws_size,
                              hipStream_t stream) {
    const float* pos     = (const float*)d_in[0];
    const float* cell    = (const float*)d_in[1];
    const int*   numbers = (const int*)d_in[2];
    float*       out     = (float*)d_out;

    unsigned* hdr  = (unsigned*)d_ws;
    float4*   cand = (float4*)((char*)d_ws + WS_CAND_OFF);
    unsigned* cidx = (unsigned*)((char*)d_ws + WS_IDX_OFF);

    hipMemsetAsync(d_ws, 0, 4, stream);  // zero compaction counter

    void* args[] = { (void*)&pos, (void*)&cell, (void*)&numbers,
                     (void*)&hdr, (void*)&cand, (void*)&cidx, (void*)&out };
    hipError_t e = hipLaunchCooperativeKernel((void*)knn_coop, dim3(COOP_GRID),
                                              dim3(256), args, 0, stream);
    if (e != hipSuccess) {
        // proven R2 path: prep + knn as separate nodes
        hipLaunchKernelGGL(prep_kernel, dim3(NCAND / 256), dim3(256), 0, stream,
                           pos, cell, numbers, hdr, cand, cidx, out);
        hipLaunchKernelGGL(knn_kernel, dim3(N_ATOMS), dim3(256), 0, stream,
                           pos, cell, hdr, cand, cidx, out);
    }
}

// Round 6
// 94.924 us; speedup vs baseline: 2.1404x; 2.1404x over previous
//
#include <hip/hip_runtime.h>
#include <stdint.h>

#define N_ATOMS 2048
#define KNN     12
#define CAP     128
#define NEDGE   (N_ATOMS * KNN)
#define OFF_EDGE 0
#define OFF_DIST (3 * NEDGE)
#define OFF_SRC  (OFF_DIST + NEDGE)
#define OFF_DST  (OFF_SRC + NEDGE)
#define OFF_NUM  (OFF_DST + NEDGE)
#define DELTA   5e-4f   // cheap-vs-exact frac guard band (cheap-test err ~2e-6)

// Single fused kernel, one block per center atom, NO workspace, NO extra nodes.
// Per thread: classify its 8 atoms via the cheap frac test (validated in R3),
// and for each candidate replica immediately compute the reference-chain d2;
// LDS traffic only on threshold hits (~48/block). Exact top-12 via 64-lane
// shfl-min on packed (d2_bits<<32 | j*2048+i) keys == lax.top_k tie-break.
__global__ __launch_bounds__(256) void knn_fused(
    const float* __restrict__ pos, const float* __restrict__ cell,
    const int* __restrict__ numbers, float* __restrict__ out)
{
    __shared__ float sh_shift[27][3];
    __shared__ unsigned long long sh_keys[CAP];
    __shared__ int sh_cnt;

    const int a = blockIdx.x;
    const int tid = threadIdx.x;

    float c[9];
#pragma unroll
    for (int q = 0; q < 9; ++q) c[q] = cell[q];

    // inverse via double adjugate, rounded to f32 (identical to passing rounds)
    double a00 = c[0], a01 = c[1], a02 = c[2];
    double a10 = c[3], a11 = c[4], a12 = c[5];
    double a20 = c[6], a21 = c[7], a22 = c[8];
    double det = a00 * (a11 * a22 - a12 * a21)
               - a01 * (a10 * a22 - a12 * a20)
               + a02 * (a10 * a21 - a11 * a20);
    double id = 1.0 / det;
    float M[9];  // frac_d = fma(pz,M[6+d], fma(py,M[3+d], px*M[d]))
    M[0] = (float)(( a11 * a22 - a12 * a21) * id);
    M[1] = (float)((-(a01 * a22 - a02 * a21)) * id);
    M[2] = (float)(( a01 * a12 - a02 * a11) * id);
    M[3] = (float)((-(a10 * a22 - a12 * a20)) * id);
    M[4] = (float)(( a00 * a22 - a02 * a20) * id);
    M[5] = (float)((-(a00 * a12 - a02 * a10)) * id);
    M[6] = (float)(( a10 * a21 - a11 * a20) * id);
    M[7] = (float)((-(a00 * a21 - a01 * a20)) * id);
    M[8] = (float)(( a00 * a11 - a01 * a10) * id);

    float rn0 = sqrtf(c[0]*c[0] + c[1]*c[1] + c[2]*c[2]);
    float rn1 = sqrtf(c[3]*c[3] + c[4]*c[4] + c[5]*c[5]);
    float rn2 = sqrtf(c[6]*c[6] + c[7]*c[7] + c[8]*c[8]);
    float dxm = 0.1f * fminf(rn0, fminf(rn1, rn2));
    const float e0 = dxm / rn0, e1 = dxm / rn1, e2 = dxm / rn2;

    float vol = (float)fabs(det);
    float T = powf(3.0f * 48.0f * vol / (4.0f * 3.14159265f * (float)N_ATOMS), 2.0f / 3.0f);

    if (tid < 27) {
        int j = tid;
        float o0 = (float)(j / 9 - 1);
        float o1 = (float)((j / 3) % 3 - 1);
        float o2 = (float)(j % 3 - 1);
        sh_shift[j][0] = __fadd_rn(__fadd_rn(__fmul_rn(o0, c[0]), __fmul_rn(o1, c[3])), __fmul_rn(o2, c[6]));
        sh_shift[j][1] = __fadd_rn(__fadd_rn(__fmul_rn(o0, c[1]), __fmul_rn(o1, c[4])), __fmul_rn(o2, c[7]));
        sh_shift[j][2] = __fadd_rn(__fadd_rn(__fmul_rn(o0, c[2]), __fmul_rn(o1, c[5])), __fmul_rn(o2, c[8]));
    }

    if (a < N_ATOMS / 256) {
        int mm = a * 256 + tid;
        out[OFF_NUM + mm] = (float)numbers[mm];
    }

    const float cx = pos[a * 3 + 0];
    const float cy = pos[a * 3 + 1];
    const float cz = pos[a * 3 + 2];
    const float cc = __fadd_rn(__fadd_rn(__fmul_rn(cx, cx), __fmul_rn(cy, cy)), __fmul_rn(cz, cz));

    int cnt = 0;
    for (int att = 0; att < 16; ++att) {
        if (tid == 0) sh_cnt = 0;
        __syncthreads();   // also covers sh_shift visibility on att==0

#pragma unroll
        for (int ch = 0; ch < N_ATOMS / 256; ++ch) {
            int i = ch * 256 + tid;
            float pxi = pos[i * 3 + 0], pyi = pos[i * 3 + 1], pzi = pos[i * 3 + 2];
            float fr0 = __fmaf_rn(pzi, M[6], __fmaf_rn(pyi, M[3], __fmul_rn(pxi, M[0])));
            float fr1 = __fmaf_rn(pzi, M[7], __fmaf_rn(pyi, M[4], __fmul_rn(pxi, M[1])));
            float fr2 = __fmaf_rn(pzi, M[8], __fmaf_rn(pyi, M[5], __fmul_rn(pxi, M[2])));
            // per dim: o=0 always valid; alt=+1 (k=2) iff fr<=e; alt=-1 (k=0) iff fr>=1-e
            int alt0 = 1, has0 = 0, unc0 = 0;
            if (fr0 <= e0 + DELTA)              { alt0 = 2; has0 = 1; unc0 = (fr0 > e0 - DELTA); }
            else if (fr0 >= 1.0f - e0 - DELTA)  { alt0 = 0; has0 = 1; unc0 = (fr0 < 1.0f - e0 + DELTA); }
            int alt1 = 1, has1 = 0, unc1 = 0;
            if (fr1 <= e1 + DELTA)              { alt1 = 2; has1 = 1; unc1 = (fr1 > e1 - DELTA); }
            else if (fr1 >= 1.0f - e1 - DELTA)  { alt1 = 0; has1 = 1; unc1 = (fr1 < 1.0f - e1 + DELTA); }
            int alt2 = 1, has2 = 0, unc2 = 0;
            if (fr2 <= e2 + DELTA)              { alt2 = 2; has2 = 1; unc2 = (fr2 > e2 - DELTA); }
            else if (fr2 >= 1.0f - e2 - DELTA)  { alt2 = 0; has2 = 1; unc2 = (fr2 < 1.0f - e2 + DELTA); }

#pragma unroll
            for (int s = 0; s < 8; ++s) {
                int s0 = s & 1, s1 = (s >> 1) & 1, s2 = (s >> 2) & 1;
                if ((s0 & (has0 ^ 1)) | (s1 & (has1 ^ 1)) | (s2 & (has2 ^ 1))) continue;
                int k0 = s0 ? alt0 : 1;
                int k1 = s1 ? alt1 : 1;
                int k2 = s2 ? alt2 : 1;
                int j = k0 * 9 + k1 * 3 + k2;
                float px = __fadd_rn(pxi, sh_shift[j][0]);
                float py = __fadd_rn(pyi, sh_shift[j][1]);
                float pz = __fadd_rn(pzi, sh_shift[j][2]);
                float pp  = __fadd_rn(__fadd_rn(__fmul_rn(px, px), __fmul_rn(py, py)), __fmul_rn(pz, pz));
                float dot = __fmaf_rn(cz, pz, __fmaf_rn(cy, py, __fmul_rn(cx, px)));
                float d2  = __fsub_rn(__fadd_rn(cc, pp), __fmul_rn(2.0f, dot));
                if (d2 < T) {
                    if (i == a && j == 13) continue;   // self
                    if ((s0 & unc0) | (s1 & unc1) | (s2 & unc2)) {
                        // boundary band: exact reference validity on shifted pos
                        float f0 = __fmaf_rn(pz, M[6], __fmaf_rn(py, M[3], __fmul_rn(px, M[0])));
                        float f1 = __fmaf_rn(pz, M[7], __fmaf_rn(py, M[4], __fmul_rn(px, M[1])));
                        float f2 = __fmaf_rn(pz, M[8], __fmaf_rn(py, M[5], __fmul_rn(px, M[2])));
                        bool v = (f0 >= -e0) && (f0 <= 1.0f + e0)
                              && (f1 >= -e1) && (f1 <= 1.0f + e1)
                              && (f2 >= -e2) && (f2 <= 1.0f + e2);
                        if (!v) continue;
                    }
                    int slot = atomicAdd(&sh_cnt, 1);
                    if (slot < CAP)
                        sh_keys[slot] = ((unsigned long long)__float_as_uint(d2) << 32)
                                      | (unsigned)(j * N_ATOMS + i);
                }
            }
        }
        __syncthreads();
        cnt = sh_cnt;
        __syncthreads();   // protect sh_cnt vs next-iter reset
        if (cnt >= KNN && cnt <= CAP) break;
        T = (cnt < KNN) ? T * 2.0f : T * 0.5f;
    }
    if (cnt > CAP) cnt = CAP;   // safety (att-loop exhaustion)

    // ---- exact top-12 extraction (wave 0) ----
    if (tid < 64) {
        const unsigned long long MAXK = ~0ull;
        unsigned long long k0 = (tid < cnt) ? sh_keys[tid] : MAXK;
        unsigned long long k1 = (tid + 64 < cnt) ? sh_keys[tid + 64] : MAXK;
        unsigned long long lo = (k0 < k1) ? k0 : k1;
        unsigned long long hi = (k0 < k1) ? k1 : k0;
#pragma unroll
        for (int r = 0; r < KNN; ++r) {
            unsigned long long mn = lo;
#pragma unroll
            for (int off = 32; off; off >>= 1) {
                unsigned long long o = __shfl_xor(mn, off, 64);
                mn = (o < mn) ? o : mn;
            }
            if (lo == mn) { lo = hi; hi = MAXK; }  // consume winner
            if (tid == r) {
                unsigned mval = (unsigned)(mn & 0xffffffffu);
                float d2 = __uint_as_float((unsigned)(mn >> 32));
                int ii = (int)(mval & (N_ATOMS - 1));
                int jj = (int)(mval >> 11);
                float px = __fadd_rn(pos[ii * 3 + 0], sh_shift[jj][0]);
                float py = __fadd_rn(pos[ii * 3 + 1], sh_shift[jj][1]);
                float pz = __fadd_rn(pos[ii * 3 + 2], sh_shift[jj][2]);
                int eo = a * KNN + r;
                out[OFF_EDGE + 3 * eo + 0] = __fsub_rn(px, cx);
                out[OFF_EDGE + 3 * eo + 1] = __fsub_rn(py, cy);
                out[OFF_EDGE + 3 * eo + 2] = __fsub_rn(pz, cz);
                out[OFF_DIST + eo] = sqrtf(fmaxf(d2, 0.0f));
                out[OFF_SRC + eo]  = (float)ii;
                out[OFF_DST + eo]  = (float)a;
            }
        }
    }
}

extern "C" void kernel_launch(void* const* d_in, const int* in_sizes, int n_in,
                              void* d_out, int out_size, void* d_ws, size_t ws_size,
                              hipStream_t stream) {
    const float* pos     = (const float*)d_in[0];
    const float* cell    = (const float*)d_in[1];
    const int*   numbers = (const int*)d_in[2];
    float*       out     = (float*)d_out;
    (void)d_ws; (void)ws_size;

    hipLaunchKernelGGL(knn_fused, dim3(N_ATOMS), dim3(256), 0, stream,
                       pos, cell, numbers, out);
}